// Round 1
// baseline (615.919 us; speedup 1.0000x reference)
//
#include <hip/hip_runtime.h>
#include <math.h>

#define DIM 2048
#define SLOTS 256
#define TSTEPS 64
#define FB (TSTEPS * DIM)          // 131072 floats
#define KQ 4                       // K-split factor: K/block = 512
#define BK 64                      // k-chunk (cols) staged per iteration
#define NBLK 512                   // mega grid size (2 blocks/CU used, >=3 capacity)

typedef unsigned short u16;
typedef __bf16 bf16x8 __attribute__((ext_vector_type(8)));
typedef float f32x4 __attribute__((ext_vector_type(4)));

union FragU { unsigned u[4]; bf16x8 v; };

__device__ __forceinline__ u16 f2bf(float f){
    union { float f; unsigned u; } v; v.f = f;
    unsigned r = v.u + 0x7fffu + ((v.u >> 16) & 1u);
    return (u16)(r >> 16);
}
__device__ __forceinline__ float sigmoidf_(float x){ return 1.0f / (1.0f + __expf(-x)); }

__device__ __forceinline__ void split8t(const float* x, bf16x8& hi, bf16x8& lo){
    FragU H, L;
    #pragma unroll
    for (int p = 0; p < 4; ++p){
        union { float f; unsigned u; } u0, u1, l0, l1;
        u0.f = x[2*p]; u1.f = x[2*p+1];
        unsigned h0 = u0.u & 0xffff0000u, h1 = u1.u & 0xffff0000u;
        H.u[p] = (h0 >> 16) | h1;
        l0.f = u0.f - __uint_as_float(h0);
        l1.f = u1.f - __uint_as_float(h1);
        L.u[p] = (l0.u >> 16) | (l1.u & 0xffff0000u);
    }
    hi = H.v; lo = L.v;
}

__device__ __forceinline__ f32x4 mfma16(bf16x8 a, bf16x8 b, f32x4 c){
    return __builtin_amdgcn_mfma_f32_16x16x32_bf16(a, b, c, 0, 0, 0);
}

// async global->LDS, 16B/lane; lds base wave-uniform, lane i lands at +i*16
__device__ __forceinline__ void gl_lds16(const float* gp, float* lp){
    __builtin_amdgcn_global_load_lds(
        (const __attribute__((address_space(1))) unsigned int*)gp,
        (__attribute__((address_space(3))) unsigned int*)lp, 16, 0, 0);
}

struct SMem { float At[64 * BK]; float Wt[16 * BK]; int flag; };

// ---------- device-scope two-level grid barrier (bar: 512 zeroed ints, single use) ----------
// 16 group counters (64B apart) + 1 final counter. acq_rel RMW = L2 writeback/inv on gfx950,
// so data written before the barrier is visible to every XCD after it.
__device__ __forceinline__ void gridbar(int* bar){
    __syncthreads();                                   // drains vmcnt for all waves
    if (threadIdx.x == 0){
        const int g = (int)(blockIdx.x & 15);
        int a = __hip_atomic_fetch_add(&bar[g * 16], 1, __ATOMIC_ACQ_REL, __HIP_MEMORY_SCOPE_AGENT);
        if (a == (NBLK / 16) - 1)
            __hip_atomic_fetch_add(&bar[256], 1, __ATOMIC_ACQ_REL, __HIP_MEMORY_SCOPE_AGENT);
        while (__hip_atomic_load(&bar[256], __ATOMIC_RELAXED, __HIP_MEMORY_SCOPE_AGENT) < 16)
            __builtin_amdgcn_s_sleep(4);
        __threadfence();                               // acquire side: invalidate L1/L2
    }
    __syncthreads();
}

// ---------------- m97-lite GEMM body (unchanged math, verified) -------------------
// Block: 256 thr / 4 waves (wave = m-quarter). Tile: 16 j-cols, K = DIM/KQ = 512,
// staged in 8 chunks of BK=64 via global_load_lds into XOR-swizzled LDS.
__device__ __forceinline__ void gemm_body(const float* __restrict__ A,
                                          const float* __restrict__ Wrow0,
                                          int kq, float* At, float* Wt, f32x4& acc)
{
    const int tid = threadIdx.x;
    const int lane = tid & 63, w = tid >> 6;
    const int s = lane & 15, rsub = lane >> 4;
    const int n4 = lane & 15;
    const int kbase = kq * (DIM / KQ);

    acc = (f32x4){0.f, 0.f, 0.f, 0.f};

    for (int c = 0; c < (DIM / KQ) / BK; ++c){
        const int kc = kbase + c * BK;
        #pragma unroll
        for (int i = 0; i < 4; ++i){
            const int rowL = w * 16 + i * 4 + rsub;
            const float* gp = A + (size_t)rowL * DIM + kc + ((s ^ (rowL & 15)) << 2);
            gl_lds16(gp, At + (w * 16 + i * 4) * BK);
        }
        {
            const int rowL = w * 4 + rsub;
            const float* gp = Wrow0 + (size_t)rowL * DIM + kc + ((s ^ (rowL & 15)) << 2);
            gl_lds16(gp, Wt + (w * 4) * BK);
        }
        __syncthreads();
        #pragma unroll
        for (int ks = 0; ks < 2; ++ks){
            const int cg0 = ks * 8 + (lane >> 4) * 2;
            const int rA = w * 16 + n4;
            float a8[8], w8[8];
            *(float4*)(a8)     = *(const float4*)&At[rA * BK + ((cg0 ^ n4) << 2)];
            *(float4*)(a8 + 4) = *(const float4*)&At[rA * BK + (((cg0 + 1) ^ n4) << 2)];
            *(float4*)(w8)     = *(const float4*)&Wt[n4 * BK + ((cg0 ^ n4) << 2)];
            *(float4*)(w8 + 4) = *(const float4*)&Wt[n4 * BK + (((cg0 + 1) ^ n4) << 2)];
            bf16x8 ah, al, wh, wl;
            split8t(a8, ah, al);
            split8t(w8, wh, wl);
            acc = mfma16(ah, wh, acc);
            acc = mfma16(al, wh, acc);
            acc = mfma16(ah, wl, acc);
        }
        __syncthreads();
    }
}

// ---------------- fused per-tile combine (sums 4 KQ partials + bias + activation) ----------
// MODE 0: relu  1: plain  2: sig(u)*sig(ps*vw+vb)  3: X*sig(u)  4: sigmoid
template<int MODE>
__device__ __forceinline__ void comb_tile(const float* __restrict__ P, int NJ, int j0,
    const float* __restrict__ bias, const float* __restrict__ vwp,
    const float* __restrict__ vbp, const float* __restrict__ Xp,
    float* __restrict__ out)
{
    const int t = threadIdx.x >> 2;
    const int j = j0 + ((threadIdx.x & 3) << 2);
    const size_t ro = (size_t)t * NJ + j;
    const size_t PS = (size_t)64 * NJ;
    float v[4], tmp[4];
    *(float4*)(v) = *(const float4*)(P + ro);
    #pragma unroll
    for (int p = 1; p < KQ; ++p){
        *(float4*)(tmp) = *(const float4*)(P + (size_t)p * PS + ro);
        #pragma unroll
        for (int c = 0; c < 4; ++c) v[c] += tmp[c];
    }
    float b4[4];
    *(float4*)(b4) = *(const float4*)(bias + j);
    float x4[4], y4[4];
    if (MODE == 2){
        *(float4*)(x4) = *(const float4*)(vwp + j);
        *(float4*)(y4) = *(const float4*)(vbp + j);
    }
    if (MODE == 3){
        *(float4*)(x4) = *(const float4*)(Xp + ro);   // NJ==DIM here
    }
    const float ps = -cosf(0.37699111843077515f * (float)(t + 1));
    float r[4];
    #pragma unroll
    for (int c = 0; c < 4; ++c){
        float u = v[c] + b4[c];
        if (MODE == 0)      r[c] = fmaxf(u, 0.f);
        else if (MODE == 1) r[c] = u;
        else if (MODE == 2) r[c] = sigmoidf_(u) * sigmoidf_(fmaf(ps, x4[c], y4[c]));
        else if (MODE == 3) r[c] = x4[c] * sigmoidf_(u);
        else                r[c] = sigmoidf_(u);
    }
    *(float4*)(out + ro) = *(const float4*)(r);
}

// ---------------- one GEMM tile + last-arriver combine ----------------
template<int MODE>
__device__ __forceinline__ void do_tile(int vb, int jt, int j0,
    const float* __restrict__ A, const float* __restrict__ W,
    float* __restrict__ Pout, int NJ,
    const float* __restrict__ bias, const float* __restrict__ vwp,
    const float* __restrict__ vbp, const float* __restrict__ Xp,
    float* __restrict__ Out, int* __restrict__ tctr,
    SMem& sm, const int* trr, const int* jrr)
{
    const int kq = vb & (KQ - 1);
    f32x4 acc;
    gemm_body(A, W + (size_t)j0 * DIM, kq, sm.At, sm.Wt, acc);
    float* outb = Pout + (size_t)kq * 64 * NJ;
    #pragma unroll
    for (int r = 0; r < 4; ++r)
        outb[(size_t)trr[r] * NJ + j0 + jrr[r]] = acc[r];
    __syncthreads();                       // all partial stores drained (vmcnt0)
    if (threadIdx.x == 0){
        __threadfence();                   // release: flush partials device-wide
        int a = __hip_atomic_fetch_add(&tctr[jt], 1, __ATOMIC_ACQ_REL, __HIP_MEMORY_SCOPE_AGENT);
        sm.flag = (a == KQ - 1) ? 1 : 0;   // acq_rel RMW also invalidates -> fresh reads below
    }
    __syncthreads();
    if (sm.flag)
        comb_tile<MODE>(Pout, NJ, j0, bias, vwp, vbp, Xp, Out);
}

// ---------------- init: zero sync counters + idx detect + prep ----------------
__global__ __launch_bounds__(256)
void init_k(const float* __restrict__ traces, const float* __restrict__ noise,
            const int* __restrict__ idxw, char* __restrict__ ws)
{
    const int tid = threadIdx.x;
    if (blockIdx.x == TSTEPS){             // zero barrier + tile counters (below pool)
        int* z = (int*)ws;
        for (int i = tid; i < 16384; i += 256) z[i] = 0;
        return;
    }
    // per-block int64 detection (no cross-block dependency)
    __shared__ int i64f;
    int v = 0;
    if (tid < 32) v = (idxw[2 * tid + 1] != 0) ? 1 : 0;
    unsigned long long bm = __ballot(v);
    if (tid == 0) i64f = (bm == 0ull) ? 1 : 0;
    __syncthreads();
    const int t = blockIdx.x;
    long row = i64f ? (long)idxw[2 * t] : (long)idxw[t];

    float* A0 = (float*)(ws + 65536);      // pool[0]
    const int k = tid * 8;
    const float* tr = traces + (size_t)row * DIM + k;
    const float* nz = noise + (size_t)t * DIM + k;
    float4 a0 = *(const float4*)(tr), a1 = *(const float4*)(tr + 4);
    float4 b0 = *(const float4*)(nz), b1 = *(const float4*)(nz + 4);
    float4 r0, r1;
    r0.x = fmaf(0.01f, b0.x, a0.x); r0.y = fmaf(0.01f, b0.y, a0.y);
    r0.z = fmaf(0.01f, b0.z, a0.z); r0.w = fmaf(0.01f, b0.w, a0.w);
    r1.x = fmaf(0.01f, b1.x, a1.x); r1.y = fmaf(0.01f, b1.y, a1.y);
    r1.z = fmaf(0.01f, b1.z, a1.z); r1.w = fmaf(0.01f, b1.w, a1.w);
    float* o = A0 + (size_t)t * DIM + k;
    *(float4*)(o) = r0; *(float4*)(o + 4) = r1;
}

// ---------------- the persistent mega kernel ----------------
__global__ __launch_bounds__(256, 3)
void mega(const float* __restrict__ W1, const float* __restrict__ b1,
          const float* __restrict__ W2, const float* __restrict__ b2,
          const float* __restrict__ Wl, const float* __restrict__ bl,
          const float* __restrict__ vw, const float* __restrict__ vb,
          const float* __restrict__ Wg, const float* __restrict__ bg,
          const float* __restrict__ Wa, const float* __restrict__ ba,
          const float* __restrict__ We, const float* __restrict__ be,
          const float* __restrict__ Wad, const float* __restrict__ bad_,
          const float* __restrict__ usage0, const float* __restrict__ mem0,
          float* __restrict__ out, char* __restrict__ ws)
{
    __shared__ SMem sm;
    int* BAR  = (int*)ws;                  // 6 barriers x 512 ints
    int* TCTR = (int*)(ws + 16384);        // 5 stages x 512 ints
    float* pool = (float*)(ws + 65536);
    float* A0v = pool;
    float* Hv  = pool + 1 * (size_t)FB;
    float* Xv  = pool + 2 * (size_t)FB;
    float* LVv = pool + 3 * (size_t)FB;
    float* Gv  = pool + 4 * (size_t)FB;
    float* ERv = pool + 5 * (size_t)FB;
    float* ADv = pool + 6 * (size_t)FB;
    float* Pp  = pool + 7 * (size_t)FB;    // 4*FB stage partials
    float* PpE = pool;                     // alias over A0,H,X,LV (dead by heads)
    float* PpA = Pp;
    float* PpL = pool + 11 * (size_t)FB;   // 4*64*256
    float* WGv = PpL + 4 * TSTEPS * SLOTS; // 64*256
    float* PpS = WGv + TSTEPS * SLOTS;     // 64*256 summed logits (+ba)

    const int tid = threadIdx.x, lane = tid & 63, w = tid >> 6;

    // ---- inline MFMA D-layout calibration (was calib_k) ----
    int trr[4], jrr[4];
    {
        const u16 oneb = 0x3F80;
        const u16 lb = f2bf((float)((lane & 15) + 1));
        FragU O, L;
        #pragma unroll
        for (int p = 0; p < 4; ++p){
            O.u[p] = ((unsigned)oneb) | (((unsigned)oneb) << 16);
            L.u[p] = ((unsigned)lb)   | (((unsigned)lb)   << 16);
        }
        f32x4 z = {0.f, 0.f, 0.f, 0.f};
        f32x4 dj = mfma16(O.v, L.v, z);
        f32x4 dt = mfma16(L.v, O.v, z);
        #pragma unroll
        for (int r = 0; r < 4; ++r){
            int jl = (int)(dj[r] * (1.0f/32.0f) + 0.5f) - 1;
            int tl = (int)(dt[r] * (1.0f/32.0f) + 0.5f) - 1;
            trr[r] = w * 16 + (tl & 15);
            jrr[r] = jl & 15;
        }
    }

    const int jt0 = (int)(blockIdx.x >> 2);

    // ---- stage 1: H = relu(A0 @ W1^T + b1) ----
    do_tile<0>((int)blockIdx.x, jt0, jt0 * 16, A0v, W1, Pp, DIM,
               b1, nullptr, nullptr, nullptr, Hv, TCTR + 0 * 512, sm, trr, jrr);
    gridbar(BAR + 0 * 512);
    // ---- stage 2: X = H @ W2^T + b2 ----
    do_tile<1>((int)blockIdx.x, jt0, jt0 * 16, Hv, W2, Pp, DIM,
               b2, nullptr, nullptr, nullptr, Xv, TCTR + 1 * 512, sm, trr, jrr);
    gridbar(BAR + 1 * 512);
    // ---- stage 3: LV = sig(X@Wl^T+bl) * sig(ps*vw+vb) ----
    do_tile<2>((int)blockIdx.x, jt0, jt0 * 16, Xv, Wl, Pp, DIM,
               bl, vw, vb, nullptr, LVv, TCTR + 2 * 512, sm, trr, jrr);
    gridbar(BAR + 2 * 512);
    // ---- stage 4: G = X * sig(LV@Wg^T+bg) ----
    do_tile<3>((int)blockIdx.x, jt0, jt0 * 16, LVv, Wg, Pp, DIM,
               bg, nullptr, nullptr, Xv, Gv, TCTR + 3 * 512, sm, trr, jrr);
    gridbar(BAR + 3 * 512);
    // ---- heads: ER = sig(G@We^T+be), AD = G@Wad^T+bad, PpS = G@Wa^T+ba ----
    for (int vbb = (int)blockIdx.x; vbb < 272 * KQ; vbb += NBLK){
        const int jt = vbb >> 2;
        if (jt < 128)
            do_tile<4>(vbb, jt, jt * 16, Gv, We, PpE, DIM,
                       be, nullptr, nullptr, nullptr, ERv, TCTR + 4 * 512, sm, trr, jrr);
        else if (jt < 256)
            do_tile<1>(vbb, jt, (jt - 128) * 16, Gv, Wad, PpA, DIM,
                       bad_, nullptr, nullptr, nullptr, ADv, TCTR + 4 * 512, sm, trr, jrr);
        else
            do_tile<1>(vbb, jt, (jt - 256) * 16, Gv, Wa, PpL, SLOTS,
                       ba, nullptr, nullptr, nullptr, PpS, TCTR + 4 * 512, sm, trr, jrr);
    }
    gridbar(BAR + 4 * 512);

    // ---- sequential softmax/usage scan (block 0, wave 0), 1-deep prefetch ----
    if (blockIdx.x == 0 && tid < 64){
        float u[4], cur[4];
        #pragma unroll
        for (int c = 0; c < 4; ++c){
            u[c]   = usage0[tid + 64 * c];
            cur[c] = PpS[tid + 64 * c];
        }
        for (int t = 0; t < TSTEPS; ++t){
            float nxt[4] = {0.f, 0.f, 0.f, 0.f};
            if (t < TSTEPS - 1){
                #pragma unroll
                for (int c = 0; c < 4; ++c) nxt[c] = PpS[(t + 1) * SLOTS + tid + 64 * c];
            }
            float e[4];
            #pragma unroll
            for (int c = 0; c < 4; ++c) e[c] = __expf(cur[c] - 0.1f * u[c]);
            float sm_ = (e[0] + e[1]) + (e[2] + e[3]);
            #pragma unroll
            for (int off = 1; off < 64; off <<= 1) sm_ += __shfl_xor(sm_, off, 64);
            float inv = 1.0f / sm_;
            float* wr = WGv + t * SLOTS;
            #pragma unroll
            for (int c = 0; c < 4; ++c){
                float ww = e[c] * inv;
                u[c] += ww;
                wr[tid + 64 * c] = ww;
            }
            #pragma unroll
            for (int c = 0; c < 4; ++c) cur[c] = nxt[c];
        }
    }
    gridbar(BAR + 5 * 512);

    // ---- memory recurrence: all 512 blocks, 4 dims each ----
    {
        const int s = tid;
        const int d0 = (int)blockIdx.x * 4;
        float m[4];
        *(float4*)(m) = *(const float4*)(mem0 + (size_t)s * DIM + d0);
        #pragma unroll 4
        for (int t = 0; t < TSTEPS; ++t){
            const size_t ro = (size_t)t * DIM + d0;
            float e4[4], a4[4];
            *(float4*)(e4) = *(const float4*)(ERv + ro);
            *(float4*)(a4) = *(const float4*)(ADv + ro);
            float wgt = 0.5f * WGv[t * SLOTS + s];
            #pragma unroll
            for (int c = 0; c < 4; ++c){
                float f = wgt * e4[c];
                float tmp = fmaf(-f, m[c], m[c]);
                m[c] = fmaf(wgt, a4[c], tmp);
            }
        }
        *(float4*)(out + (size_t)s * DIM + d0) = *(const float4*)(m);
    }
}

extern "C" void kernel_launch(void* const* d_in, const int* in_sizes, int n_in,
                              void* d_out, int out_size, void* d_ws, size_t ws_size,
                              hipStream_t stream)
{
    const float* traces = (const float*)d_in[0];
    const float* noise  = (const float*)d_in[1];
    const float* mem0   = (const float*)d_in[2];
    const float* usage0 = (const float*)d_in[3];
    const float* W1 = (const float*)d_in[4];  const float* b1 = (const float*)d_in[5];
    const float* W2 = (const float*)d_in[6];  const float* b2 = (const float*)d_in[7];
    const float* Wl = (const float*)d_in[8];  const float* bl = (const float*)d_in[9];
    const float* vw = (const float*)d_in[10]; const float* vb = (const float*)d_in[11];
    const float* Wg = (const float*)d_in[12]; const float* bg = (const float*)d_in[13];
    const float* Wa = (const float*)d_in[14]; const float* ba = (const float*)d_in[15];
    const float* We = (const float*)d_in[16]; const float* be = (const float*)d_in[17];
    const float* Wad = (const float*)d_in[18]; const float* bad_ = (const float*)d_in[19];
    const int* idx = (const int*)d_in[20];

    char* ws = (char*)d_ws;

    init_k<<<TSTEPS + 1, 256, 0, stream>>>(traces, noise, idx, ws);
    mega<<<NBLK, 256, 0, stream>>>(W1, b1, W2, b2, Wl, bl, vw, vb, Wg, bg,
                                   Wa, ba, We, be, Wad, bad_,
                                   usage0, mem0, (float*)d_out, ws);
}

// Round 2
// 290.139 us; speedup vs baseline: 2.1228x; 2.1228x over previous
//
#include <hip/hip_runtime.h>
#include <math.h>

#define DIM 2048
#define SLOTS 256
#define TSTEPS 64
#define FB (TSTEPS * DIM)          // 131072 floats
#define KQ 8                       // K-split factor: K/block = 256
#define KS (DIM / KQ)              // 256 k-cols per block
#define BK 64                      // k-chunk per compute iteration
#define NC (KS / BK)               // 4 chunks
#define JG 32                      // j-cols per block (2 tiles of 16)

typedef unsigned short u16;
typedef __bf16 bf16x8 __attribute__((ext_vector_type(8)));
typedef float f32x4 __attribute__((ext_vector_type(4)));

union FragU { unsigned u[4]; bf16x8 v; };

__device__ __forceinline__ u16 f2bf(float f){
    union { float f; unsigned u; } v; v.f = f;
    unsigned r = v.u + 0x7fffu + ((v.u >> 16) & 1u);
    return (u16)(r >> 16);
}
__device__ __forceinline__ float sigmoidf_(float x){ return 1.0f / (1.0f + __expf(-x)); }

__device__ __forceinline__ void split8t(const float* x, bf16x8& hi, bf16x8& lo){
    FragU H, L;
    #pragma unroll
    for (int p = 0; p < 4; ++p){
        union { float f; unsigned u; } u0, u1, l0, l1;
        u0.f = x[2*p]; u1.f = x[2*p+1];
        unsigned h0 = u0.u & 0xffff0000u, h1 = u1.u & 0xffff0000u;
        H.u[p] = (h0 >> 16) | h1;
        l0.f = u0.f - __uint_as_float(h0);
        l1.f = u1.f - __uint_as_float(h1);
        L.u[p] = (l0.u >> 16) | (l1.u & 0xffff0000u);
    }
    hi = H.v; lo = L.v;
}

__device__ __forceinline__ f32x4 mfma16(bf16x8 a, bf16x8 b, f32x4 c){
    return __builtin_amdgcn_mfma_f32_16x16x32_bf16(a, b, c, 0, 0, 0);
}

// async global->LDS, 16B/lane; lds base wave-uniform, lane i lands at +i*16
__device__ __forceinline__ void gl_lds16(const float* gp, float* lp){
    __builtin_amdgcn_global_load_lds(
        (const __attribute__((address_space(1))) unsigned int*)gp,
        (__attribute__((address_space(3))) unsigned int*)lp, 16, 0, 0);
}

// ---- inline MFMA D-layout calibration (2 MFMAs, per block) ----
__device__ __forceinline__ void calib_inline(int lane, int w, int* trr, int* jrr){
    const u16 oneb = 0x3F80;
    const u16 lb = f2bf((float)((lane & 15) + 1));
    FragU O, L;
    #pragma unroll
    for (int p = 0; p < 4; ++p){
        O.u[p] = ((unsigned)oneb) | (((unsigned)oneb) << 16);
        L.u[p] = ((unsigned)lb)   | (((unsigned)lb)   << 16);
    }
    f32x4 z = {0.f, 0.f, 0.f, 0.f};
    f32x4 dj = mfma16(O.v, L.v, z);
    f32x4 dt = mfma16(L.v, O.v, z);
    #pragma unroll
    for (int r = 0; r < 4; ++r){
        int jl = (int)(dj[r] * (1.0f/32.0f) + 0.5f) - 1;
        int tl = (int)(dt[r] * (1.0f/32.0f) + 0.5f) - 1;
        trr[r] = w * 16 + (tl & 15);
        jrr[r] = jl & 15;
    }
}

// ---------------- A-resident-LDS, W-streaming GEMM block ----------------
// LDS: A-slice [4 chunks][64 rows][BK] (64 KB, loaded once) + W dbuf 2x[16][BK] (8 KB).
// Per block: j-group of 32 cols (2 tiles of 16), k-slice of 256 (kq of 8).
struct GSm { float A[NC * 64 * BK]; float Wb[2][16 * BK]; };

__device__ __forceinline__ void gemm_block(const float* __restrict__ A,
                                           const float* __restrict__ Wg0, // + j0*DIM
                                           int kq, GSm& sm, f32x4* acc)
{
    const int tid = threadIdx.x;
    const int lane = tid & 63, w = tid >> 6;
    const int s = lane & 15, rsub = lane >> 4;
    const int n4 = lane & 15;
    const int kbase = kq * KS;

    // ---- stage A-slice once: 16 gl_lds16 per wave ----
    #pragma unroll
    for (int c = 0; c < NC; ++c)
        #pragma unroll
        for (int i = 0; i < 4; ++i){
            const int rowL = w * 16 + i * 4 + rsub;
            const float* gp = A + (size_t)rowL * DIM + kbase + c * BK + ((s ^ (rowL & 15)) << 2);
            gl_lds16(gp, sm.A + (c * 64 + w * 16 + i * 4) * BK);
        }
    // ---- W chunk 0 (jt=0,c=0) into Wb[0] ----
    {
        const int rowL = w * 4 + rsub;
        const float* gp = Wg0 + (size_t)rowL * DIM + kbase + ((s ^ (rowL & 15)) << 2);
        gl_lds16(gp, sm.Wb[0] + (w * 4) * BK);
    }
    __syncthreads();

    acc[0] = (f32x4){0.f, 0.f, 0.f, 0.f};
    acc[1] = (f32x4){0.f, 0.f, 0.f, 0.f};

    #pragma unroll
    for (int it = 0; it < 2 * NC; ++it){
        const int jt = it >> 2, c = it & 3;
        const int bufc = it & 1;
        // prefetch next W chunk into the other buffer
        if (it + 1 < 2 * NC){
            const int nj = (it + 1) >> 2, ncc = (it + 1) & 3;
            const int rowL = w * 4 + rsub;
            const float* gp = Wg0 + (size_t)(nj * 16 + rowL) * DIM
                            + kbase + ncc * BK + ((s ^ (rowL & 15)) << 2);
            gl_lds16(gp, sm.Wb[bufc ^ 1] + (w * 4) * BK);
        }
        const float* At = sm.A + c * 64 * BK;
        const float* Wt = sm.Wb[bufc];
        #pragma unroll
        for (int ks = 0; ks < 2; ++ks){
            const int cg0 = ks * 8 + (lane >> 4) * 2;
            const int rA = w * 16 + n4;
            float a8[8], w8[8];
            *(float4*)(a8)     = *(const float4*)&At[rA * BK + ((cg0 ^ n4) << 2)];
            *(float4*)(a8 + 4) = *(const float4*)&At[rA * BK + (((cg0 + 1) ^ n4) << 2)];
            *(float4*)(w8)     = *(const float4*)&Wt[n4 * BK + ((cg0 ^ n4) << 2)];
            *(float4*)(w8 + 4) = *(const float4*)&Wt[n4 * BK + (((cg0 + 1) ^ n4) << 2)];
            bf16x8 ah, al, wh, wl;
            split8t(a8, ah, al);
            split8t(w8, wh, wl);
            if (jt == 0){
                acc[0] = mfma16(ah, wh, acc[0]);
                acc[0] = mfma16(al, wh, acc[0]);
                acc[0] = mfma16(ah, wl, acc[0]);
            } else {
                acc[1] = mfma16(ah, wh, acc[1]);
                acc[1] = mfma16(al, wh, acc[1]);
                acc[1] = mfma16(ah, wl, acc[1]);
            }
        }
        __syncthreads();   // drains prefetch (vmcnt0) + protects Wb ping-pong
    }
}

// stage GEMM: grid = 64 jg x 8 kq = 512; partial out Pp[kq][64][DIM]
__global__ __launch_bounds__(256)
void gemm_s(const float* __restrict__ A, const float* __restrict__ W,
            float* __restrict__ Pp)
{
    __shared__ GSm sm;
    const int kq = blockIdx.x & (KQ - 1);
    const int jg = blockIdx.x >> 3;
    const int j0 = jg * JG;
    const int lane = threadIdx.x & 63, w = threadIdx.x >> 6;
    int trr[4], jrr[4];
    calib_inline(lane, w, trr, jrr);
    f32x4 acc[2];
    gemm_block(A, W + (size_t)j0 * DIM, kq, sm, acc);
    float* outb = Pp + (size_t)kq * FB;
    #pragma unroll
    for (int jt = 0; jt < 2; ++jt)
        #pragma unroll
        for (int r = 0; r < 4; ++r)
            outb[(size_t)trr[r] * DIM + j0 + jt * 16 + jrr[r]] = acc[jt][r];
}

// heads GEMM: grid = (64 We + 64 Wad + 8 Wa) x 8 kq = 1088
__global__ __launch_bounds__(256)
void gemm_h(const float* __restrict__ G,
            const float* __restrict__ We, const float* __restrict__ Wad,
            const float* __restrict__ Wa,
            float* __restrict__ PpE, float* __restrict__ PpA, float* __restrict__ PpL)
{
    __shared__ GSm sm;
    const int kq = blockIdx.x & (KQ - 1);
    const int jg = blockIdx.x >> 3;
    const float* W; float* out; int j0, NJ;
    if (jg < 64)       { W = We;  out = PpE; j0 = jg * JG;        NJ = DIM; }
    else if (jg < 128) { W = Wad; out = PpA; j0 = (jg - 64) * JG; NJ = DIM; }
    else               { W = Wa;  out = PpL; j0 = (jg - 128) * JG; NJ = SLOTS; }
    const int lane = threadIdx.x & 63, w = threadIdx.x >> 6;
    int trr[4], jrr[4];
    calib_inline(lane, w, trr, jrr);
    f32x4 acc[2];
    gemm_block(G, W + (size_t)j0 * DIM, kq, sm, acc);
    float* outb = out + (size_t)kq * 64 * NJ;
    #pragma unroll
    for (int jt = 0; jt < 2; ++jt)
        #pragma unroll
        for (int r = 0; r < 4; ++r)
            outb[(size_t)trr[r] * NJ + j0 + jt * 16 + jrr[r]] = acc[jt][r];
}

// ---------------- combine 8 partials + bias + activation (NJ = DIM) ----------------
// MODE 0: relu  1: plain  2: sig(u)*sig(ps*vw+vb)  3: X*sig(u)  4: sigmoid
template<int MODE>
__device__ __forceinline__ void comb_core(int bb, const float* __restrict__ P,
    const float* __restrict__ bias, const float* __restrict__ vwp,
    const float* __restrict__ vbp, const float* __restrict__ Xp,
    float* __restrict__ out)
{
    const size_t i0 = ((size_t)bb * 256 + threadIdx.x) * 8;
    const int t = (int)(i0 >> 11);
    const int j = (int)(i0 & (DIM - 1));
    float v[8], tmp[8];
    *(float4*)(v)     = *(const float4*)(P + i0);
    *(float4*)(v + 4) = *(const float4*)(P + i0 + 4);
    #pragma unroll
    for (int p = 1; p < KQ; ++p){
        *(float4*)(tmp)     = *(const float4*)(P + (size_t)p * FB + i0);
        *(float4*)(tmp + 4) = *(const float4*)(P + (size_t)p * FB + i0 + 4);
        #pragma unroll
        for (int c = 0; c < 8; ++c) v[c] += tmp[c];
    }
    float b8[8];
    *(float4*)(b8)     = *(const float4*)(bias + j);
    *(float4*)(b8 + 4) = *(const float4*)(bias + j + 4);
    float x8[8], y8[8];
    if (MODE == 2){
        *(float4*)(x8)     = *(const float4*)(vwp + j);
        *(float4*)(x8 + 4) = *(const float4*)(vwp + j + 4);
        *(float4*)(y8)     = *(const float4*)(vbp + j);
        *(float4*)(y8 + 4) = *(const float4*)(vbp + j + 4);
    }
    if (MODE == 3){
        *(float4*)(x8)     = *(const float4*)(Xp + i0);
        *(float4*)(x8 + 4) = *(const float4*)(Xp + i0 + 4);
    }
    const float ps = -cosf(0.37699111843077515f * (float)(t + 1));
    float r[8];
    #pragma unroll
    for (int c = 0; c < 8; ++c){
        float u = v[c] + b8[c];
        if (MODE == 0)      r[c] = fmaxf(u, 0.f);
        else if (MODE == 1) r[c] = u;
        else if (MODE == 2) r[c] = sigmoidf_(u) * sigmoidf_(fmaf(ps, x8[c], y8[c]));
        else if (MODE == 3) r[c] = x8[c] * sigmoidf_(u);
        else                r[c] = sigmoidf_(u);
    }
    *(float4*)(out + i0)     = *(const float4*)(r);
    *(float4*)(out + i0 + 4) = *(const float4*)(r + 4);
}

template<int MODE>
__global__ __launch_bounds__(256)
void comb8(const float* __restrict__ P, const float* __restrict__ bias,
           const float* __restrict__ vwp, const float* __restrict__ vbp,
           const float* __restrict__ Xp, float* __restrict__ out)
{
    comb_core<MODE>((int)blockIdx.x, P, bias, vwp, vbp, Xp, out);
}

// ---------------- fused: ER-comb (blocks 0-63) + AD-comb (64-127) + scan (128) -------
__global__ __launch_bounds__(256)
void comb_ea_scan(const float* __restrict__ PpE, const float* __restrict__ be,
                  const float* __restrict__ PpA, const float* __restrict__ bad_,
                  const float* __restrict__ PpL, const float* __restrict__ ba,
                  const float* __restrict__ usage0,
                  float* __restrict__ ER, float* __restrict__ AD,
                  float* __restrict__ WG)
{
    const int b = (int)blockIdx.x;
    if (b < 64){
        comb_core<4>(b, PpE, be, nullptr, nullptr, nullptr, ER);
        return;
    }
    if (b < 128){
        comb_core<1>(b - 64, PpA, bad_, nullptr, nullptr, nullptr, AD);
        return;
    }
    // ---- block 128: sequential softmax/usage scan, 1-deep prefetch ----
    const int tid = threadIdx.x;
    if (tid >= 64) return;
    const int PS = TSTEPS * SLOTS;
    float u[4], bv[4], cur[4];
    #pragma unroll
    for (int c = 0; c < 4; ++c){
        const int sl = tid + 64 * c;
        u[c]  = usage0[sl];
        bv[c] = ba[sl];
        float s = bv[c];
        #pragma unroll
        for (int p = 0; p < KQ; ++p) s += PpL[p * PS + sl];
        cur[c] = s;
    }
    for (int t = 0; t < TSTEPS; ++t){
        float nxt[4] = {0.f, 0.f, 0.f, 0.f};
        if (t < TSTEPS - 1){
            #pragma unroll
            for (int c = 0; c < 4; ++c){
                const int sl = (t + 1) * SLOTS + tid + 64 * c;
                float s = bv[c];
                #pragma unroll
                for (int p = 0; p < KQ; ++p) s += PpL[p * PS + sl];
                nxt[c] = s;
            }
        }
        float e[4];
        #pragma unroll
        for (int c = 0; c < 4; ++c) e[c] = __expf(cur[c] - 0.1f * u[c]);
        float sm_ = (e[0] + e[1]) + (e[2] + e[3]);
        #pragma unroll
        for (int off = 1; off < 64; off <<= 1) sm_ += __shfl_xor(sm_, off, 64);
        float inv = 1.0f / sm_;
        float* wr = WG + t * SLOTS;
        #pragma unroll
        for (int c = 0; c < 4; ++c){
            float ww = e[c] * inv;
            u[c] += ww;
            wr[tid + 64 * c] = ww;
        }
        #pragma unroll
        for (int c = 0; c < 4; ++c) cur[c] = nxt[c];
    }
}

// ---------------- init: idx detect + gather/noise prep ----------------
__global__ __launch_bounds__(256)
void init_k(const float* __restrict__ traces, const float* __restrict__ noise,
            const int* __restrict__ idxw, float* __restrict__ A0)
{
    const int tid = threadIdx.x;
    __shared__ int i64f;
    int v = 0;
    if (tid < 32) v = (idxw[2 * tid + 1] != 0) ? 1 : 0;
    unsigned long long bm = __ballot(v);
    if (tid == 0) i64f = (bm == 0ull) ? 1 : 0;
    __syncthreads();
    const int t = blockIdx.x;
    long row = i64f ? (long)idxw[2 * t] : (long)idxw[t];
    const int k = tid * 8;
    const float* tr = traces + (size_t)row * DIM + k;
    const float* nz = noise + (size_t)t * DIM + k;
    float4 a0 = *(const float4*)(tr), a1 = *(const float4*)(tr + 4);
    float4 b0 = *(const float4*)(nz), b1 = *(const float4*)(nz + 4);
    float4 r0, r1;
    r0.x = fmaf(0.01f, b0.x, a0.x); r0.y = fmaf(0.01f, b0.y, a0.y);
    r0.z = fmaf(0.01f, b0.z, a0.z); r0.w = fmaf(0.01f, b0.w, a0.w);
    r1.x = fmaf(0.01f, b1.x, a1.x); r1.y = fmaf(0.01f, b1.y, a1.y);
    r1.z = fmaf(0.01f, b1.z, a1.z); r1.w = fmaf(0.01f, b1.w, a1.w);
    float* o = A0 + (size_t)t * DIM + k;
    *(float4*)(o) = r0; *(float4*)(o + 4) = r1;
}

// ---------------- memory recurrence ----------------
__global__ __launch_bounds__(256)
void mem_k(const float* __restrict__ mem0, const float* __restrict__ wgt,
           const float* __restrict__ ER, const float* __restrict__ AD,
           float* __restrict__ out)
{
    const int s = threadIdx.x;
    const int d0 = blockIdx.x * 8;
    float m[8];
    *(float4*)(m)     = *(const float4*)(mem0 + (size_t)s * DIM + d0);
    *(float4*)(m + 4) = *(const float4*)(mem0 + (size_t)s * DIM + d0 + 4);
    for (int t = 0; t < TSTEPS; ++t){
        const size_t ro = (size_t)t * DIM + d0;
        float e8[8], a8[8];
        *(float4*)(e8)     = *(const float4*)(ER + ro);
        *(float4*)(e8 + 4) = *(const float4*)(ER + ro + 4);
        *(float4*)(a8)     = *(const float4*)(AD + ro);
        *(float4*)(a8 + 4) = *(const float4*)(AD + ro + 4);
        float w = 0.5f * wgt[t * SLOTS + s];
        #pragma unroll
        for (int c = 0; c < 8; ++c){
            float f = w * e8[c];
            float tmp = fmaf(-f, m[c], m[c]);
            m[c] = fmaf(w, a8[c], tmp);
        }
    }
    float* op = out + (size_t)s * DIM + d0;
    *(float4*)(op)     = *(const float4*)(m);
    *(float4*)(op + 4) = *(const float4*)(m + 4);
}

extern "C" void kernel_launch(void* const* d_in, const int* in_sizes, int n_in,
                              void* d_out, int out_size, void* d_ws, size_t ws_size,
                              hipStream_t stream)
{
    const float* traces = (const float*)d_in[0];
    const float* noise  = (const float*)d_in[1];
    const float* mem0   = (const float*)d_in[2];
    const float* usage0 = (const float*)d_in[3];
    const float* W1 = (const float*)d_in[4];  const float* b1 = (const float*)d_in[5];
    const float* W2 = (const float*)d_in[6];  const float* b2 = (const float*)d_in[7];
    const float* Wl = (const float*)d_in[8];  const float* bl = (const float*)d_in[9];
    const float* vw = (const float*)d_in[10]; const float* vb = (const float*)d_in[11];
    const float* Wg = (const float*)d_in[12]; const float* bg = (const float*)d_in[13];
    const float* Wa = (const float*)d_in[14]; const float* ba = (const float*)d_in[15];
    const float* We = (const float*)d_in[16]; const float* be = (const float*)d_in[17];
    const float* Wad = (const float*)d_in[18]; const float* bad_ = (const float*)d_in[19];
    const int* idx = (const int*)d_in[20];

    float* pool = (float*)d_ws;
    float* A0v = pool + 0 * (size_t)FB;
    float* Hv  = pool + 1 * (size_t)FB;
    float* Xv  = pool + 2 * (size_t)FB;
    float* LVv = pool + 3 * (size_t)FB;
    float* Gv  = pool + 4 * (size_t)FB;
    float* ERv = pool + 5 * (size_t)FB;
    float* ADv = pool + 6 * (size_t)FB;
    float* Pp  = pool + 7 * (size_t)FB;          // 8*FB stage partials
    float* PpE = pool + 15 * (size_t)FB;         // 8*FB
    float* PpA = pool + 23 * (size_t)FB;         // 8*FB
    float* PpL = pool + 31 * (size_t)FB;         // 8*64*256 = 1*FB
    float* WGv = pool + 32 * (size_t)FB;         // 64*256

    init_k<<<TSTEPS, 256, 0, stream>>>(traces, noise, idx, A0v);

    gemm_s<<<64 * KQ, 256, 0, stream>>>(A0v, W1, Pp);
    comb8<0><<<64, 256, 0, stream>>>(Pp, b1, nullptr, nullptr, nullptr, Hv);
    gemm_s<<<64 * KQ, 256, 0, stream>>>(Hv, W2, Pp);
    comb8<1><<<64, 256, 0, stream>>>(Pp, b2, nullptr, nullptr, nullptr, Xv);
    gemm_s<<<64 * KQ, 256, 0, stream>>>(Xv, Wl, Pp);
    comb8<2><<<64, 256, 0, stream>>>(Pp, bl, vw, vb, nullptr, LVv);
    gemm_s<<<64 * KQ, 256, 0, stream>>>(LVv, Wg, Pp);
    comb8<3><<<64, 256, 0, stream>>>(Pp, bg, nullptr, nullptr, Xv, Gv);

    gemm_h<<<136 * KQ, 256, 0, stream>>>(Gv, We, Wad, Wa, PpE, PpA, PpL);
    comb_ea_scan<<<129, 256, 0, stream>>>(PpE, be, PpA, bad_, PpL, ba, usage0,
                                          ERv, ADv, WGv);
    mem_k<<<DIM / 8, 256, 0, stream>>>(mem0, WGv, ERv, ADv, (float*)d_out);
}